// Round 4
// baseline (4908.221 us; speedup 1.0000x reference)
//
#include <hip/hip_runtime.h>
#include <hip/hip_bf16.h>
#include <math.h>

#define T_STEPS 256
#define BATCH   128
#define IN_DIM  1024
#define LAT     2048

typedef __bf16 bf16x8 __attribute__((ext_vector_type(8)));
typedef __bf16 bf16x4 __attribute__((ext_vector_type(4)));
typedef float  f32x4  __attribute__((ext_vector_type(4)));

// ---------------------------------------------------------------------------
// LDS tile helpers for k_xproj: [ROWS][32] bf16, row stride 64 B, XOR-swizzle
// (same transform write+read -> bijective).
// ---------------------------------------------------------------------------
__device__ __forceinline__ int swz(int row, int kbyte) {
    return (row * 64 + kbyte) ^ ((row & 7) << 4);
}

template<int ROWS>
__device__ __forceinline__ void stage_load(const float* __restrict__ src, int ld,
                                           int tid, f32x4* regs) {
#pragma unroll
    for (int rnd = 0; rnd < ROWS / 32; ++rnd) {
        int r  = rnd * 32 + (tid >> 3);
        int kc = (tid & 7) * 4;
        regs[rnd] = *(const f32x4*)(src + (size_t)r * ld + kc);
    }
}

template<int ROWS>
__device__ __forceinline__ void stage_write(const f32x4* regs, char* hi, char* lo,
                                            int tid) {
#pragma unroll
    for (int rnd = 0; rnd < ROWS / 32; ++rnd) {
        int r  = rnd * 32 + (tid >> 3);
        int kc = (tid & 7) * 4;
        bf16x4 vh, vl;
        f32x4  v = regs[rnd];
#pragma unroll
        for (int e = 0; e < 4; ++e) {
            float x = v[e];
            __bf16 h = (__bf16)x;
            vh[e] = h;
            vl[e] = (__bf16)(x - (float)h);
        }
        int off = swz(r, kc * 2);
        *(bf16x4*)(hi + off) = vh;
        *(bf16x4*)(lo + off) = vl;
    }
}

__device__ __forceinline__ bf16x8 ld_frag(const char* p, int row, int kb) {
    return *(const bf16x8*)(p + swz(row, kb));
}

__device__ __forceinline__ void split8(f32x4 v0, f32x4 v1, bf16x8& hi, bf16x8& lo) {
#pragma unroll
    for (int e = 0; e < 4; ++e) {
        __bf16 h0 = (__bf16)v0[e];
        hi[e]     = h0;
        lo[e]     = (__bf16)(v0[e] - (float)h0);
        __bf16 h1 = (__bf16)v1[e];
        hi[e + 4] = h1;
        lo[e + 4] = (__bf16)(v1[e] - (float)h1);
    }
}

// ---------------------------------------------------------------------------
// Prep: Wh (fp32 [2048][2048]) -> split bf16 planes hi/lo. Runs once.
// ---------------------------------------------------------------------------
__global__ __launch_bounds__(256)
void k_prep(const float* __restrict__ W, __bf16* __restrict__ hi,
            __bf16* __restrict__ lo)
{
    size_t i = ((size_t)blockIdx.x * 256 + threadIdx.x) * 4;
    f32x4 v = *(const f32x4*)(W + i);
    bf16x4 vh, vl;
#pragma unroll
    for (int e = 0; e < 4; ++e) {
        __bf16 h = (__bf16)v[e];
        vh[e] = h;
        vl[e] = (__bf16)(v[e] - (float)h);
    }
    *(bf16x4*)(hi + i) = vh;
    *(bf16x4*)(lo + i) = vl;
}

// ---------------------------------------------------------------------------
// Phase 1: xi = x @ W_i^T + b_i -> out (fp32); t==0 rows get tanh and (fast
// path) also seed the h-split ping buffer.
// ---------------------------------------------------------------------------
__global__ __launch_bounds__(256, 2)
void k_xproj(const float* __restrict__ x, const float* __restrict__ Wi,
             const float* __restrict__ bi, float* __restrict__ out,
             __bf16* __restrict__ h0hi, __bf16* __restrict__ h0lo)
{
    __shared__ __align__(16) char lds[32 * 1024];
    char* Ahi = lds;
    char* Alo = lds + 8192;
    char* Bhi = lds + 16384;
    char* Blo = lds + 24576;

    int tid  = threadIdx.x;
    int lane = tid & 63;
    int w    = tid >> 6;
    int wm   = (w >> 1) * 64;
    int wn   = (w & 1) * 64;
    int bm   = blockIdx.y * 128;
    int bn   = blockIdx.x * 128;

    const float* Abase = x  + (size_t)bm * IN_DIM;
    const float* Bbase = Wi + (size_t)bn * IN_DIM;

    f32x4 acc[4][4] = {};
    f32x4 ra[4], rb[4];

    stage_load<128>(Abase, IN_DIM, tid, ra);
    stage_load<128>(Bbase, IN_DIM, tid, rb);

    for (int k0 = 0; k0 < IN_DIM; k0 += 32) {
        stage_write<128>(ra, Ahi, Alo, tid);
        stage_write<128>(rb, Bhi, Blo, tid);
        __syncthreads();

        if (k0 + 32 < IN_DIM) {
            stage_load<128>(Abase + k0 + 32, IN_DIM, tid, ra);
            stage_load<128>(Bbase + k0 + 32, IN_DIM, tid, rb);
        }

        int kb = (lane >> 4) * 16;
        bf16x8 ah[4], al[4], bh[4], bl[4];
#pragma unroll
        for (int i = 0; i < 4; ++i) {
            int rrow = i * 16 + (lane & 15);
            ah[i] = ld_frag(Ahi, wm + rrow, kb);
            al[i] = ld_frag(Alo, wm + rrow, kb);
            bh[i] = ld_frag(Bhi, wn + rrow, kb);
            bl[i] = ld_frag(Blo, wn + rrow, kb);
        }
#pragma unroll
        for (int i = 0; i < 4; ++i)
#pragma unroll
            for (int j = 0; j < 4; ++j) {
                acc[i][j] = __builtin_amdgcn_mfma_f32_16x16x32_bf16(ah[i], bh[j], acc[i][j], 0, 0, 0);
                acc[i][j] = __builtin_amdgcn_mfma_f32_16x16x32_bf16(ah[i], bl[j], acc[i][j], 0, 0, 0);
                acc[i][j] = __builtin_amdgcn_mfma_f32_16x16x32_bf16(al[i], bh[j], acc[i][j], 0, 0, 0);
            }
        __syncthreads();
    }

#pragma unroll
    for (int j = 0; j < 4; ++j) {
        int n = bn + wn + j * 16 + (lane & 15);
        float bias = bi[n];
#pragma unroll
        for (int i = 0; i < 4; ++i) {
            int m0 = bm + wm + i * 16 + ((lane >> 4) * 4);
#pragma unroll
            for (int r = 0; r < 4; ++r) {
                float v = acc[i][j][r] + bias;
                if (m0 + r < BATCH) {
                    v = tanhf(v);                       // t == 0: h0 = tanh(xi)
                    if (h0hi) {                         // seed split-h ping[0]
                        __bf16 hh = (__bf16)v;
                        size_t hidx = (size_t)(m0 + r) * LAT + n;
                        h0hi[hidx] = hh;
                        h0lo[hidx] = (__bf16)(v - (float)hh);
                    }
                }
                out[(size_t)(m0 + r) * LAT + n] = v;
            }
        }
    }
}

// ---------------------------------------------------------------------------
// Phase 2 (v4): io[m][n] = tanh(io[m][n] + h @ Wh^T + bh) with h and Wh
// pre-split to bf16 hi/lo planes. 256 blocks x 512 threads (8 waves), WG tile
// 32x32, wave w owns K in [w*256, w*256+256). Inner loop is pure loads+MFMA.
// Epilogue writes fp32 h_t to out AND split-bf16 h_t to the next ping buffer.
// ---------------------------------------------------------------------------
__global__ __launch_bounds__(512, 1)
void k_step2(const __bf16* __restrict__ Ah, const __bf16* __restrict__ Al,
             const __bf16* __restrict__ Bh, const __bf16* __restrict__ Bl,
             const float* __restrict__ bias, float* __restrict__ io,
             __bf16* __restrict__ Nh, __bf16* __restrict__ Nl)
{
    __shared__ __align__(16) float part[8][32][32];   // 32 KB

    const int tid  = threadIdx.x;
    const int lane = tid & 63;
    const int w    = tid >> 6;            // wave id == K-split index (0..7)

    const int id  = blockIdx.x;           // XCD-local decode (id&7 == xcd)
    const int j_  = id >> 3;
    const int bn  = ((id & 7) * 8 + (j_ >> 2)) * 32;
    const int bm  = (j_ & 3) * 32;

    const int fr = lane & 15;
    const int kq = (lane >> 4) * 8;

    const __bf16* A0h = Ah + (size_t)(bm + fr) * LAT;
    const __bf16* A1h = A0h + 16 * LAT;
    const __bf16* A0l = Al + (size_t)(bm + fr) * LAT;
    const __bf16* A1l = A0l + 16 * LAT;
    const __bf16* B0h = Bh + (size_t)(bn + fr) * LAT;
    const __bf16* B1h = B0h + 16 * LAT;
    const __bf16* B0l = Bl + (size_t)(bn + fr) * LAT;
    const __bf16* B1l = B0l + 16 * LAT;

    f32x4 acc[2][2] = {};
    const int kbase = w * 256 + kq;

#pragma unroll
    for (int i = 0; i < 8; ++i) {
        const int k = kbase + i * 32;
        bf16x8 ah0 = *(const bf16x8*)(A0h + k);
        bf16x8 ah1 = *(const bf16x8*)(A1h + k);
        bf16x8 al0 = *(const bf16x8*)(A0l + k);
        bf16x8 al1 = *(const bf16x8*)(A1l + k);
        bf16x8 bh0 = *(const bf16x8*)(B0h + k);
        bf16x8 bh1 = *(const bf16x8*)(B1h + k);
        bf16x8 bl0 = *(const bf16x8*)(B0l + k);
        bf16x8 bl1 = *(const bf16x8*)(B1l + k);

        acc[0][0] = __builtin_amdgcn_mfma_f32_16x16x32_bf16(ah0, bh0, acc[0][0], 0, 0, 0);
        acc[0][1] = __builtin_amdgcn_mfma_f32_16x16x32_bf16(ah0, bh1, acc[0][1], 0, 0, 0);
        acc[1][0] = __builtin_amdgcn_mfma_f32_16x16x32_bf16(ah1, bh0, acc[1][0], 0, 0, 0);
        acc[1][1] = __builtin_amdgcn_mfma_f32_16x16x32_bf16(ah1, bh1, acc[1][1], 0, 0, 0);

        acc[0][0] = __builtin_amdgcn_mfma_f32_16x16x32_bf16(al0, bh0, acc[0][0], 0, 0, 0);
        acc[0][1] = __builtin_amdgcn_mfma_f32_16x16x32_bf16(al0, bh1, acc[0][1], 0, 0, 0);
        acc[1][0] = __builtin_amdgcn_mfma_f32_16x16x32_bf16(al1, bh0, acc[1][0], 0, 0, 0);
        acc[1][1] = __builtin_amdgcn_mfma_f32_16x16x32_bf16(al1, bh1, acc[1][1], 0, 0, 0);

        acc[0][0] = __builtin_amdgcn_mfma_f32_16x16x32_bf16(ah0, bl0, acc[0][0], 0, 0, 0);
        acc[0][1] = __builtin_amdgcn_mfma_f32_16x16x32_bf16(ah0, bl1, acc[0][1], 0, 0, 0);
        acc[1][0] = __builtin_amdgcn_mfma_f32_16x16x32_bf16(ah1, bl0, acc[1][0], 0, 0, 0);
        acc[1][1] = __builtin_amdgcn_mfma_f32_16x16x32_bf16(ah1, bl1, acc[1][1], 0, 0, 0);
    }

    // C-frag layout (m89): col = lane&15, row = (lane>>4)*4 + reg.
#pragma unroll
    for (int mi = 0; mi < 2; ++mi)
#pragma unroll
        for (int nj = 0; nj < 2; ++nj)
#pragma unroll
            for (int r = 0; r < 4; ++r)
                part[w][mi * 16 + (lane >> 4) * 4 + r][nj * 16 + fr] = acc[mi][nj][r];

    __syncthreads();

    // 512 threads combine 8 partials: each owns 2 consecutive cols of one row.
    const int row = tid >> 4;
    const int c   = (tid & 15) * 2;
    float s0 = 0.f, s1 = 0.f;
#pragma unroll
    for (int p = 0; p < 8; ++p) {
        s0 += part[p][row][c];
        s1 += part[p][row][c + 1];
    }
    const size_t idx = (size_t)(bm + row) * LAT + bn + c;
    float o0 = tanhf(s0 + bias[bn + c]     + io[idx]);
    float o1 = tanhf(s1 + bias[bn + c + 1] + io[idx + 1]);
    io[idx]     = o0;
    io[idx + 1] = o1;
    __bf16 h0 = (__bf16)o0, h1 = (__bf16)o1;
    Nh[idx]     = h0;
    Nh[idx + 1] = h1;
    Nl[idx]     = (__bf16)(o0 - (float)h0);
    Nl[idx + 1] = (__bf16)(o1 - (float)h1);
}

// ---------------------------------------------------------------------------
// Fallback step (round-3 path) if ws_size is too small for the split planes.
// ---------------------------------------------------------------------------
__global__ __launch_bounds__(256, 2)
void k_step_f32(const float* __restrict__ hprev, const float* __restrict__ Wh,
                const float* __restrict__ bias, float* __restrict__ io)
{
    __shared__ __align__(16) float part[4][32][32];

    const int tid  = threadIdx.x;
    const int lane = tid & 63;
    const int w    = tid >> 6;

    const int id  = blockIdx.x;
    const int j_  = id >> 3;
    const int bn  = ((id & 7) * 8 + (j_ >> 2)) * 32;
    const int bm  = (j_ & 3) * 32;

    const int fr = lane & 15;
    const int kq = (lane >> 4) * 8;

    const float* A0 = hprev + (size_t)(bm + fr)      * LAT;
    const float* A1 = hprev + (size_t)(bm + 16 + fr) * LAT;
    const float* B0 = Wh    + (size_t)(bn + fr)      * LAT;
    const float* B1 = Wh    + (size_t)(bn + 16 + fr) * LAT;

    f32x4 acc[2][2] = {};
    const int kbase = w * 512 + kq;
#pragma unroll
    for (int i = 0; i < 16; ++i) {
        const int k = kbase + i * 32;
        f32x4 a00 = *(const f32x4*)(A0 + k);
        f32x4 a01 = *(const f32x4*)(A0 + k + 4);
        f32x4 a10 = *(const f32x4*)(A1 + k);
        f32x4 a11 = *(const f32x4*)(A1 + k + 4);
        f32x4 b00 = *(const f32x4*)(B0 + k);
        f32x4 b01 = *(const f32x4*)(B0 + k + 4);
        f32x4 b10 = *(const f32x4*)(B1 + k);
        f32x4 b11 = *(const f32x4*)(B1 + k + 4);

        bf16x8 ah0, al0, ah1, al1, bh0, bl0, bh1, bl1;
        split8(a00, a01, ah0, al0);
        split8(a10, a11, ah1, al1);
        split8(b00, b01, bh0, bl0);
        split8(b10, b11, bh1, bl1);

        acc[0][0] = __builtin_amdgcn_mfma_f32_16x16x32_bf16(ah0, bh0, acc[0][0], 0, 0, 0);
        acc[0][1] = __builtin_amdgcn_mfma_f32_16x16x32_bf16(ah0, bh1, acc[0][1], 0, 0, 0);
        acc[1][0] = __builtin_amdgcn_mfma_f32_16x16x32_bf16(ah1, bh0, acc[1][0], 0, 0, 0);
        acc[1][1] = __builtin_amdgcn_mfma_f32_16x16x32_bf16(ah1, bh1, acc[1][1], 0, 0, 0);
        acc[0][0] = __builtin_amdgcn_mfma_f32_16x16x32_bf16(al0, bh0, acc[0][0], 0, 0, 0);
        acc[0][1] = __builtin_amdgcn_mfma_f32_16x16x32_bf16(al0, bh1, acc[0][1], 0, 0, 0);
        acc[1][0] = __builtin_amdgcn_mfma_f32_16x16x32_bf16(al1, bh0, acc[1][0], 0, 0, 0);
        acc[1][1] = __builtin_amdgcn_mfma_f32_16x16x32_bf16(al1, bh1, acc[1][1], 0, 0, 0);
        acc[0][0] = __builtin_amdgcn_mfma_f32_16x16x32_bf16(ah0, bl0, acc[0][0], 0, 0, 0);
        acc[0][1] = __builtin_amdgcn_mfma_f32_16x16x32_bf16(ah0, bl1, acc[0][1], 0, 0, 0);
        acc[1][0] = __builtin_amdgcn_mfma_f32_16x16x32_bf16(ah1, bl0, acc[1][0], 0, 0, 0);
        acc[1][1] = __builtin_amdgcn_mfma_f32_16x16x32_bf16(ah1, bl1, acc[1][1], 0, 0, 0);
    }

#pragma unroll
    for (int mi = 0; mi < 2; ++mi)
#pragma unroll
        for (int nj = 0; nj < 2; ++nj)
#pragma unroll
            for (int r = 0; r < 4; ++r)
                part[w][mi * 16 + (lane >> 4) * 4 + r][nj * 16 + fr] = acc[mi][nj][r];

    __syncthreads();

    const int row = tid >> 3;
    const int c   = (tid & 7) * 4;
    f32x4 s0 = *(const f32x4*)&part[0][row][c];
    f32x4 s1 = *(const f32x4*)&part[1][row][c];
    f32x4 s2 = *(const f32x4*)&part[2][row][c];
    f32x4 s3 = *(const f32x4*)&part[3][row][c];

    float* outp = io + (size_t)(bm + row) * LAT + bn + c;
    f32x4 xv = *(const f32x4*)outp;
    f32x4 bv = *(const f32x4*)(bias + bn + c);
    f32x4 o;
#pragma unroll
    for (int e = 0; e < 4; ++e)
        o[e] = tanhf(s0[e] + s1[e] + s2[e] + s3[e] + xv[e] + bv[e]);
    *(f32x4*)outp = o;
}

extern "C" void kernel_launch(void* const* d_in, const int* in_sizes, int n_in,
                              void* d_out, int out_size, void* d_ws, size_t ws_size,
                              hipStream_t stream) {
    const float* x  = (const float*)d_in[0];
    const float* Wi = (const float*)d_in[1];
    const float* bi = (const float*)d_in[2];
    const float* Wh = (const float*)d_in[3];
    const float* bh = (const float*)d_in[4];
    float* out = (float*)d_out;

    const size_t whbytes = (size_t)LAT * LAT * 2;    // 8 MB per Wh plane
    const size_t hbytes  = (size_t)BATCH * LAT * 2;  // 512 KB per h plane
    const size_t need    = 2 * whbytes + 4 * hbytes; // 18 MB
    const bool fast = ws_size >= need;

    char* wsb = (char*)d_ws;
    __bf16* Whi   = (__bf16*)wsb;
    __bf16* Wlo   = (__bf16*)(wsb + whbytes);
    __bf16* ph[2] = { (__bf16*)(wsb + 2 * whbytes),
                      (__bf16*)(wsb + 2 * whbytes + 2 * hbytes) };
    __bf16* pl[2] = { (__bf16*)(wsb + 2 * whbytes + hbytes),
                      (__bf16*)(wsb + 2 * whbytes + 3 * hbytes) };

    if (fast)
        k_prep<<<(LAT * LAT) / (256 * 4), 256, 0, stream>>>(Wh, Whi, Wlo);

    dim3 g1(LAT / 128, (T_STEPS * BATCH) / 128);     // (16, 256)
    k_xproj<<<g1, 256, 0, stream>>>(x, Wi, bi, out,
                                    fast ? ph[0] : nullptr,
                                    fast ? pl[0] : nullptr);

    if (fast) {
        for (int t = 1; t < T_STEPS; ++t) {
            int cur = (t - 1) & 1, nxt = t & 1;
            k_step2<<<256, 512, 0, stream>>>(ph[cur], pl[cur], Whi, Wlo, bh,
                                             out + (size_t)t * BATCH * LAT,
                                             ph[nxt], pl[nxt]);
        }
    } else {
        for (int t = 1; t < T_STEPS; ++t)
            k_step_f32<<<256, 256, 0, stream>>>(out + (size_t)(t - 1) * BATCH * LAT,
                                                Wh, bh,
                                                out + (size_t)t * BATCH * LAT);
    }
}